// Round 9
// baseline (323.501 us; speedup 1.0000x reference)
//
#include <hip/hip_runtime.h>
#include <stdint.h>

#define NROWS 65536
#define HD 1024

typedef __attribute__((ext_vector_type(8))) short bf16x8;   // 8 bf16 in 4 VGPRs
typedef __attribute__((ext_vector_type(16))) float f32x16;  // MFMA 32x32 accumulator

typedef __attribute__((address_space(1))) const unsigned int* gas_ptr;
typedef __attribute__((address_space(3))) unsigned int* las_ptr;

__device__ __forceinline__ unsigned short f2bf(float f) {
  union { float f; uint32_t u; } v; v.f = f;
  uint32_t u = v.u;
  return (unsigned short)((u + 0x7fffu + ((u >> 16) & 1u)) >> 16);  // RNE
}

__device__ __forceinline__ void gl16(const void* g, void* l) {
  __builtin_amdgcn_global_load_lds((gas_ptr)g, (las_ptr)l, 16, 0, 0);
}

// ---------------- prep: W2 fp32 -> bf16, swizzled granules (unchanged) ----------------
// W2bf[c][k]; 16B granule g stored at (g&~3) | ((g&3) ^ ((c>>1)&3)).
__global__ void k_w2bf(const float* __restrict__ W2, unsigned short* __restrict__ W2bf) {
  int i = blockIdx.x * 256 + threadIdx.x;   // 131072 threads, 1 granule each
  int c = i >> 7, g = i & 127;
  const float4* s4 = (const float4*)(W2 + (size_t)c * HD + g * 8);
  float4 a = s4[0], b = s4[1];
  uint4 pk;
  pk.x = (uint32_t)f2bf(a.x) | ((uint32_t)f2bf(a.y) << 16);
  pk.y = (uint32_t)f2bf(a.z) | ((uint32_t)f2bf(a.w) << 16);
  pk.z = (uint32_t)f2bf(b.x) | ((uint32_t)f2bf(b.y) << 16);
  pk.w = (uint32_t)f2bf(b.z) | ((uint32_t)f2bf(b.w) << 16);
  int gs = (g & 124) | ((g & 3) ^ ((c >> 1) & 3));
  *(uint4*)(W2bf + (size_t)c * HD + gs * 8) = pk;
}

// ---------------- layer 1: h bf16 [65536][1024], PLAIN row-major (A is reg-direct now) ----------------
__global__ __launch_bounds__(512) void k_layer1(
    const float* __restrict__ x, const float* __restrict__ W1,
    const float* __restrict__ b1, const float* __restrict__ Wmeta,
    const float* __restrict__ bmeta, unsigned short* __restrict__ h) {
  __shared__ float xs[128 * 12];
  int r0 = blockIdx.x * 128;
  int t = threadIdx.x;
  int j0 = t * 2;
  float w1a = W1[j0], w1b = W1[j0 + 1];
  float b1a = b1[j0], b1b = b1[j0 + 1];
  float wma[10], wmb[10], bma[10], bmb[10];
#pragma unroll
  for (int e = 0; e < 10; e++) {
    float2 wmv = *(const float2*)(Wmeta + e * HD + j0);
    float2 bmv = *(const float2*)(bmeta + e * HD + j0);
    wma[e] = wmv.x; wmb[e] = wmv.y; bma[e] = bmv.x; bmb[e] = bmv.y;
  }
  for (int i = t; i < 128 * 12; i += 512) xs[i] = x[(size_t)r0 * 12 + i];
  __syncthreads();
  for (int r = 0; r < 128; r++) {
    const float* xr = xs + r * 12;
    float delta = xr[10], phi = xr[11];
    float s1a = 0.f, s1b = 0.f, s2a = 0.f, s2b = 0.f;
#pragma unroll
    for (int e = 0; e < 10; e++) {
      float oh = xr[e];
      s1a = fmaf(oh, wma[e], s1a);
      s1b = fmaf(oh, wmb[e], s1b);
      s2a = fmaf(oh, bma[e], s2a);
      s2b = fmaf(oh, bmb[e], s2b);
    }
    float pa = fmaf(delta, w1a, b1a) + fmaf(phi, s1a, s2a);
    float pb = fmaf(delta, w1b, b1b) + fmaf(phi, s1b, s2b);
    pa = fmaxf(pa, 0.f); pb = fmaxf(pb, 0.f);
    uint32_t pk = (uint32_t)f2bf(pa) | ((uint32_t)f2bf(pb) << 16);
    *(uint32_t*)(h + (size_t)(r0 + r) * HD + j0) = pk;   // plain, coalesced
  }
}

// ---------------- layers 2+3: R5 structure, A register-direct, B via LDS ----------------
// grid 4096 (XCD-swizzled) = 512 rt x 8 ct; 256 threads = 4 waves (2x2), wave tile 64x64
// = 2x2 of 32x32x16 bf16 MFMA (acc 64 AGPR). Per K-tile(64):
//   {8 A-frag global_load_dwordx4 -> regs | stage B 16KB (4 gl_lds/thread) |
//    __syncthreads (drains vmcnt) | 8 ds_read_b128 (B frags) + 16 MFMA | __syncthreads}.
// LDS port per tile: 16KB write + 32KB read (B only) vs 96KB in R5 -> LDS no longer binding.
// A global pattern identical to the old gl_lds reads (32x32B segments, L2/L3-resident h).
__global__ __launch_bounds__(256, 4) void k_gemm(
    const unsigned short* __restrict__ h, const unsigned short* __restrict__ W2bf,
    const float* __restrict__ b2, const float* __restrict__ W3,
    float* __restrict__ partial) {
  __shared__ char lds[34816];   // B panels @0/8192 (16KB); epilogue reuses 33792 B
  int tid = threadIdx.x;
  // XCD swizzle: 4096 blocks = 8 XCDs x 512; XCD k gets contiguous logical range.
  int b = (int)blockIdx.x;
  int bx = ((b & 7) << 9) | (b >> 3);
  int rt = bx >> 3, ct = bx & 7;   // 8 consecutive bx share rt -> A-panel L2 reuse
  size_t r0 = (size_t)rt * 128;
  int c0 = ct * 128;
  int w = tid >> 6, lane = tid & 63;
  int wm = w >> 1, wn = w & 1;
  int l31 = lane & 31, hi = lane >> 5;
  int sw = (l31 >> 1) & 3;   // B granule swizzle key (row bases are multiples of 32)

  f32x16 acc[2][2];
#pragma unroll
  for (int rb = 0; rb < 2; rb++)
#pragma unroll
    for (int cb = 0; cb < 2; cb++)
#pragma unroll
      for (int i = 0; i < 16; i++) acc[rb][cb][i] = 0.f;

  int brow0 = (wn * 64 + 0  + l31) * 64;
  int brow1 = (wn * 64 + 32 + l31) * 64;
  // A-frag base: row = r0 + wm*64 + l31 (+32 for rb1), k = T*64 + p*32 + kl*16 + hi*8
  const unsigned short* aBase = h + (r0 + wm * 64 + l31) * (size_t)HD + hi * 8;

  for (int T = 0; T < 16; T++) {
    // 1) A fragments straight to registers (8 x global_load_dwordx4)
    const unsigned short* at = aBase + T * 64;
    bf16x8 a000 = *(const bf16x8*)(at + 0);             // rb0 p0 kl0
    bf16x8 a001 = *(const bf16x8*)(at + 16);            // rb0 p0 kl1
    bf16x8 a010 = *(const bf16x8*)(at + 32);            // rb0 p1 kl0
    bf16x8 a011 = *(const bf16x8*)(at + 48);            // rb0 p1 kl1
    const unsigned short* at1 = at + 32 * (size_t)HD;
    bf16x8 a100 = *(const bf16x8*)(at1 + 0);            // rb1 p0 kl0
    bf16x8 a101 = *(const bf16x8*)(at1 + 16);           // rb1 p0 kl1
    bf16x8 a110 = *(const bf16x8*)(at1 + 32);           // rb1 p1 kl0
    bf16x8 a111 = *(const bf16x8*)(at1 + 48);           // rb1 p1 kl1
    // 2) stage B tile (panels p0@0, p1@8192; dest lane-linear; source pre-swizzled)
#pragma unroll
    for (int q = 0; q < 2; q++) {
      int s = tid + 256 * q;            // 0..511
      int row = s >> 2, g4 = s & 3;
      const unsigned short* wsrc = W2bf + (size_t)(c0 + row) * HD + T * 64 + g4 * 8;
      gl16(wsrc,      lds +        (size_t)s * 16);
      gl16(wsrc + 32, lds + 8192 + (size_t)s * 16);
    }
    __syncthreads();   // drains vmcnt: A regs + B tile ready; prior B reads done
    // 3) B frag reads + MFMA
#pragma unroll
    for (int p = 0; p < 2; p++) {
      const char* lB = lds + p * 8192;
#pragma unroll
      for (int kl = 0; kl < 2; kl++) {
        int slot = ((kl * 2 + hi) ^ sw) << 4;
        bf16x8 b0 = *(const bf16x8*)(lB + brow0 + slot);
        bf16x8 b1 = *(const bf16x8*)(lB + brow1 + slot);
        bf16x8 a0, a1;
        if (p == 0 && kl == 0) { a0 = a000; a1 = a100; }
        else if (p == 0)       { a0 = a001; a1 = a101; }
        else if (kl == 0)      { a0 = a010; a1 = a110; }
        else                   { a0 = a011; a1 = a111; }
        acc[0][0] = __builtin_amdgcn_mfma_f32_32x32x16_bf16(a0, b0, acc[0][0], 0, 0, 0);
        acc[0][1] = __builtin_amdgcn_mfma_f32_32x32x16_bf16(a0, b1, acc[0][1], 0, 0, 0);
        acc[1][0] = __builtin_amdgcn_mfma_f32_32x32x16_bf16(a1, b0, acc[1][0], 0, 0, 0);
        acc[1][1] = __builtin_amdgcn_mfma_f32_32x32x16_bf16(a1, b1, acc[1][1], 0, 0, 0);
      }
    }
    __syncthreads();
  }

  // ---- epilogue (R5 verbatim): v = relu(acc+b2); o = v x W3^T; LDS transpose-reduce ----
  float b2c[2], w30[2], w31[2];
#pragma unroll
  for (int cb = 0; cb < 2; cb++) {
    int c = c0 + wn * 64 + cb * 32 + l31;
    b2c[cb] = b2[c];
    w30[cb] = W3[c];
    w31[cb] = W3[HD + c];
  }
  // padded layout: line = (wm*32+rowf)*2 + wn in [0,128); float2 slot = line*33 + l31
  float2* sE = (float2*)lds;
#pragma unroll
  for (int rb = 0; rb < 2; rb++) {
    __syncthreads();
#pragma unroll
    for (int reg = 0; reg < 16; reg++) {
      float v0 = fmaxf(acc[rb][0][reg] + b2c[0], 0.f);
      float v1 = fmaxf(acc[rb][1][reg] + b2c[1], 0.f);
      float2 o;
      o.x = v0 * w30[0] + v1 * w30[1];
      o.y = v0 * w31[0] + v1 * w31[1];
      int rowf = (reg & 3) + 8 * (reg >> 2) + 4 * hi;   // verified C/D row map
      int line = (wm * 32 + rowf) * 2 + wn;
      sE[line * 33 + l31] = o;
    }
    __syncthreads();
    // reduce: 128 targets (bi 2 x rowf 32 x d 2), 2 threads each (half = wn index)
    int half = tid & 1, tgt = tid >> 1;
    int d = tgt & 1, rowf_t = (tgt >> 1) & 31, bi = tgt >> 6;
    int line0 = (bi * 32 + rowf_t) * 2 + half;
    const float* sf = (const float*)lds;
    float s = 0.f;
#pragma unroll
    for (int j = 0; j < 32; j++) s += sf[(line0 * 33 + j) * 2 + d];
    s += __shfl_xor(s, 1);
    if (half == 0) {
      int row = bi * 64 + rb * 32 + rowf_t;
      partial[(size_t)ct * (NROWS * 2) + (r0 + row) * 2 + d] = s;
    }
  }
}

// ---------------- final: out = b3 + sum over 8 col-tile partials ----------------
__global__ void k_reduce(const float* __restrict__ partial, const float* __restrict__ b3,
                         float* __restrict__ out) {
  int i = blockIdx.x * 256 + threadIdx.x;  // 131072
  float s = b3[i & 1];
#pragma unroll
  for (int ctt = 0; ctt < 8; ctt++) s += partial[(size_t)ctt * 131072 + i];
  out[i] = s;
}

extern "C" void kernel_launch(void* const* d_in, const int* in_sizes, int n_in,
                              void* d_out, int out_size, void* d_ws, size_t ws_size,
                              hipStream_t stream) {
  const float* x     = (const float*)d_in[0];
  const float* W1    = (const float*)d_in[1];
  const float* b1    = (const float*)d_in[2];
  const float* Wmeta = (const float*)d_in[3];
  const float* bmeta = (const float*)d_in[4];
  const float* W2    = (const float*)d_in[5];
  const float* b2    = (const float*)d_in[6];
  const float* W3    = (const float*)d_in[7];
  const float* b3    = (const float*)d_in[8];
  float* out = (float*)d_out;

  char* ws = (char*)d_ws;
  unsigned short* hbuf  = (unsigned short*)ws;                              // 128 MiB
  unsigned short* W2bf  = (unsigned short*)(ws + (size_t)NROWS * HD * 2);   // 2 MiB
  float* partial = (float*)(ws + (size_t)NROWS * HD * 2 + (size_t)HD * HD * 2);  // 4 MiB (8 slices)

  k_w2bf<<<512, 256, 0, stream>>>(W2, W2bf);
  k_layer1<<<512, 512, 0, stream>>>(x, W1, b1, Wmeta, bmeta, hbuf);
  k_gemm<<<4096, 256, 0, stream>>>(hbuf, W2bf, b2, W3, partial);
  k_reduce<<<512, 256, 0, stream>>>(partial, b3, out);
}